// Round 3
// baseline (1356.862 us; speedup 1.0000x reference)
//
#include <hip/hip_runtime.h>
#include <math.h>

#define BATCH 131072

// ---------------------------------------------------------------------------
// Fused GEMM (+ optional input affine/lrelu) (+ optional BN stats accumulate)
// C[r,n] = sum_k f(A[r,k]) * W[k,n] + bias[n],   f = lrelu(x*sc+sh) or identity
//
// A-tile: row-major [MT][KS], 16B-group XOR swizzle: float4 group k4 of row r
// is stored at position p = k4 ^ ((r/TM)&3).  Fragment read = ds_read_b128 of
// 4 k's, 4 distinct ty-rows -> distinct banks, broadcast across tx lanes.
// B-tile: row-major [KS][NT], linear (reads are contiguous per tx -> <=4/bank).
// Pipeline: double-buffered LDS; next chunk's global loads issue BEFORE
// compute, ds_writes after, one barrier per chunk (T14 async-stage).
// ---------------------------------------------------------------------------
template<int MT, int NT, int NSTORE, int TM, int TN, int BLK, int KS, int KPAD,
         int KRT, bool AFFINE, bool STATS>
__global__ __launch_bounds__(BLK)
void gemm_bn(const float* __restrict__ Ain, const float* __restrict__ W,
             const float* __restrict__ bias, const float* __restrict__ sc,
             const float* __restrict__ sh, float* __restrict__ Xout,
             double* __restrict__ gsum, double* __restrict__ gsq)
{
    constexpr int KC  = KPAD / KS;            // chunks
    constexpr int DB  = (KC > 1) ? 2 : 1;     // LDS buffers
    constexpr int CPR = KS / 4;               // float4 groups per row
    constexpr int NCG = NT / TN;
    constexpr int RG  = MT / TM;
    constexpr int NH  = TN / 4;
    constexpr int AL4 = MT * KS / 4 / BLK;    // A float4 loads / thread / chunk
    constexpr bool BVEC = (NT == NSTORE);
    constexpr int BL4 = BVEC ? (KS * NT / 4 / BLK) : 1;
    constexpr int BLS = BVEC ? 1 : (KS * NT / BLK);
    static_assert(NCG * RG == BLK, "thread mapping");
    static_assert(MT * KS >= 4 * BLK, "A staging divisibility");
    static_assert(!STATS || 2 * RG * NT <= DB * KS * NT, "stats scratch fits Bs");

    __shared__ float As[DB][MT][KS];
    __shared__ float Bs[DB][KS][NT];
    __shared__ float scs[AFFINE ? KPAD : 1];
    __shared__ float shs[AFFINE ? KPAD : 1];

    const int tid = threadIdx.x;
    const int r0  = blockIdx.x * MT;
    const int tx  = tid % NCG;
    const int ty  = tid / NCG;
    const int sty = ty & 3;

    float acc[TM][TN] = {};

    // ---- staging helpers -------------------------------------------------
    auto loadA = [&](int kc, float4* av) {
        #pragma unroll
        for (int l = 0; l < AL4; ++l) {
            int idx = tid + l * BLK;
            int row = idx / CPR;
            int c4  = idx % CPR;
            int gk  = kc * KS + c4 * 4;
            const float* gp = Ain + (size_t)(r0 + row) * KRT + gk;
            if constexpr (KRT == KPAD) {
                av[l] = *reinterpret_cast<const float4*>(gp);
            } else {
                if (gk + 4 <= KRT) av[l] = *reinterpret_cast<const float4*>(gp);
                else {
                    float t[4];
                    #pragma unroll
                    for (int c = 0; c < 4; ++c) t[c] = (gk + c < KRT) ? gp[c] : 0.f;
                    av[l] = make_float4(t[0], t[1], t[2], t[3]);
                }
            }
        }
    };
    auto storeA = [&](int kc, const float4* av, int d) {
        #pragma unroll
        for (int l = 0; l < AL4; ++l) {
            int idx = tid + l * BLK;
            int row = idx / CPR;
            int c4  = idx % CPR;
            float4 v = av[l];
            if constexpr (AFFINE) {
                int k0 = kc * KS + c4 * 4;
                float* vp = &v.x;
                #pragma unroll
                for (int c = 0; c < 4; ++c) {
                    float x = vp[c] * scs[k0 + c] + shs[k0 + c];
                    vp[c] = x > 0.f ? x : 0.2f * x;
                }
            }
            int p = c4 ^ ((row / TM) & 3);
            *reinterpret_cast<float4*>(&As[d][row][p * 4]) = v;
        }
    };
    auto loadB = [&](int kc, float4* bv, float* bsc) {
        if constexpr (BVEC) {
            #pragma unroll
            for (int l = 0; l < BL4; ++l) {
                int idx = tid + l * BLK;
                int kk  = idx / (NT / 4);
                int n4  = idx % (NT / 4);
                int gk  = kc * KS + kk;
                if constexpr (KRT == KPAD)
                    bv[l] = *reinterpret_cast<const float4*>(W + (size_t)gk * NSTORE + n4 * 4);
                else
                    bv[l] = (gk < KRT)
                        ? *reinterpret_cast<const float4*>(W + (size_t)gk * NSTORE + n4 * 4)
                        : make_float4(0.f, 0.f, 0.f, 0.f);
            }
        } else {
            #pragma unroll
            for (int l = 0; l < BLS; ++l) {
                int idx = tid + l * BLK;
                int kk  = idx / NT;
                int n   = idx % NT;
                int gk  = kc * KS + kk;
                bsc[l] = (gk < KRT && n < NSTORE) ? W[(size_t)gk * NSTORE + n] : 0.f;
            }
        }
    };
    auto storeB = [&](const float4* bv, const float* bsc, int d) {
        if constexpr (BVEC) {
            #pragma unroll
            for (int l = 0; l < BL4; ++l) {
                int idx = tid + l * BLK;
                int kk  = idx / (NT / 4);
                int n4  = idx % (NT / 4);
                *reinterpret_cast<float4*>(&Bs[d][kk][n4 * 4]) = bv[l];
            }
        } else {
            #pragma unroll
            for (int l = 0; l < BLS; ++l) {
                int idx = tid + l * BLK;
                Bs[d][idx / NT][idx % NT] = bsc[l];
            }
        }
    };
    auto compute = [&](int d) {
        #pragma unroll
        for (int k4 = 0; k4 < CPR; ++k4) {
            float4 a4[TM];
            const int p = (k4 ^ sty);
            #pragma unroll
            for (int i = 0; i < TM; ++i)
                a4[i] = *reinterpret_cast<const float4*>(&As[d][ty * TM + i][p * 4]);
            #pragma unroll
            for (int kk = 0; kk < 4; ++kk) {
                float b[TN];
                #pragma unroll
                for (int h = 0; h < NH; ++h)
                    *reinterpret_cast<float4*>(&b[h * 4]) =
                        *reinterpret_cast<const float4*>(&Bs[d][k4 * 4 + kk][h * (NCG * 4) + tx * 4]);
                #pragma unroll
                for (int i = 0; i < TM; ++i) {
                    const float av = (&a4[i].x)[kk];
                    #pragma unroll
                    for (int j = 0; j < TN; ++j)
                        acc[i][j] = fmaf(av, b[j], acc[i][j]);
                }
            }
        }
    };

    // ---- prologue --------------------------------------------------------
    if constexpr (AFFINE) {
        if (tid < KPAD) { scs[tid] = sc[tid]; shs[tid] = sh[tid]; }
    }

    if constexpr (KC == 1) {
        // single chunk (P1): batched load->store staging, no pipeline
        if constexpr (AFFINE) __syncthreads();
        #pragma unroll
        for (int l0 = 0; l0 < AL4; l0 += 4) {
            float4 t[4];
            constexpr int NB = (AL4 < 4) ? AL4 : 4;
            #pragma unroll
            for (int q = 0; q < NB; ++q) {
                float4 tv[1];
                // reuse loadA logic per element
                int idx = tid + (l0 + q) * BLK;
                int row = idx / CPR;
                int c4  = idx % CPR;
                int gk  = c4 * 4;
                const float* gp = Ain + (size_t)(r0 + row) * KRT + gk;
                if (gk + 4 <= KRT) tv[0] = *reinterpret_cast<const float4*>(gp);
                else {
                    float tt[4];
                    #pragma unroll
                    for (int c = 0; c < 4; ++c) tt[c] = (gk + c < KRT) ? gp[c] : 0.f;
                    tv[0] = make_float4(tt[0], tt[1], tt[2], tt[3]);
                }
                t[q] = tv[0];
            }
            #pragma unroll
            for (int q = 0; q < NB; ++q) {
                int idx = tid + (l0 + q) * BLK;
                int row = idx / CPR;
                int c4  = idx % CPR;
                int p   = c4 ^ ((row / TM) & 3);
                *reinterpret_cast<float4*>(&As[0][row][p * 4]) = t[q];
            }
        }
        #pragma unroll
        for (int l0 = 0; l0 < BL4; l0 += 4) {
            float4 t[4];
            constexpr int NB = (BL4 < 4) ? BL4 : 4;
            #pragma unroll
            for (int q = 0; q < NB; ++q) {
                int idx = tid + (l0 + q) * BLK;
                int kk  = idx / (NT / 4);
                int n4  = idx % (NT / 4);
                t[q] = (kk < KRT)
                    ? *reinterpret_cast<const float4*>(W + (size_t)kk * NSTORE + n4 * 4)
                    : make_float4(0.f, 0.f, 0.f, 0.f);
            }
            #pragma unroll
            for (int q = 0; q < NB; ++q) {
                int idx = tid + (l0 + q) * BLK;
                *reinterpret_cast<float4*>(&Bs[0][idx / (NT / 4)][(idx % (NT / 4)) * 4]) = t[q];
            }
        }
        __syncthreads();
        compute(0);
        __syncthreads();
    } else {
        float4 av[AL4];
        float4 bv[BL4];
        float  bsc[BLS];
        loadA(0, av); loadB(0, bv, bsc);
        if constexpr (AFFINE) __syncthreads();   // scs visible before transform
        storeA(0, av, 0); storeB(bv, bsc, 0);
        __syncthreads();
        #pragma unroll 2
        for (int kc = 0; kc < KC; ++kc) {
            const int cur = kc & 1;
            if (kc + 1 < KC) { loadA(kc + 1, av); loadB(kc + 1, bv, bsc); }
            compute(cur);
            if (kc + 1 < KC) { storeA(kc + 1, av, cur ^ 1); storeB(bv, bsc, cur ^ 1); }
            __syncthreads();
        }
    }

    // ---- epilogue: bias, store, BN stats ---------------------------------
    float bc[TN];
    #pragma unroll
    for (int j = 0; j < TN; ++j) {
        int gc = (j >> 2) * (NCG * 4) + tx * 4 + (j & 3);
        bc[j] = (gc < NSTORE) ? bias[gc] : 0.f;
    }
    float psum[TN] = {}, psq[TN] = {};
    #pragma unroll
    for (int i = 0; i < TM; ++i) {
        int row = r0 + ty * TM + i;
        float x[TN];
        #pragma unroll
        for (int j = 0; j < TN; ++j) {
            x[j] = acc[i][j] + bc[j];
            if (STATS) { psum[j] += x[j]; psq[j] += x[j] * x[j]; }
        }
        if constexpr (BVEC) {
            #pragma unroll
            for (int h = 0; h < NH; ++h) {
                float4 v = make_float4(x[h*4], x[h*4+1], x[h*4+2], x[h*4+3]);
                *reinterpret_cast<float4*>(
                    &Xout[(size_t)row * NSTORE + h * (NCG * 4) + tx * 4]) = v;
            }
        } else {
            #pragma unroll
            for (int j = 0; j < TN; ++j) {
                int gc = (j >> 2) * (NCG * 4) + tx * 4 + (j & 3);
                if (gc < NSTORE) Xout[(size_t)row * NSTORE + gc] = x[j];
            }
        }
    }
    if constexpr (STATS) {
        float* S1 = &Bs[0][0][0];
        float* S2 = S1 + RG * NT;
        #pragma unroll
        for (int j = 0; j < TN; ++j) {
            int gc = (j >> 2) * (NCG * 4) + tx * 4 + (j & 3);
            S1[ty * NT + gc] = psum[j];
            S2[ty * NT + gc] = psq[j];
        }
        __syncthreads();
        if (tid < NT) {
            double s = 0.0, q = 0.0;
            #pragma unroll 4
            for (int t = 0; t < RG; ++t) {
                s += (double)S1[t * NT + tid];
                q += (double)S2[t * NT + tid];
            }
            atomicAdd(&gsum[tid], s);
            atomicAdd(&gsq[tid], q);
        }
    }
}

// mu/var -> scale/shift in double:  y = x*scale + shift == (x-mu)*rsqrt(var+eps)*g + be
__global__ void finalize_bn(const double* __restrict__ sum, const double* __restrict__ sq,
                            const float* __restrict__ g, const float* __restrict__ be,
                            float* __restrict__ sc, float* __restrict__ sh, int N)
{
    int i = threadIdx.x;
    if (i < N) {
        const double inv = 1.0 / (double)BATCH;
        double mu  = sum[i] * inv;
        double var = sq[i] * inv - mu * mu;
        double s   = (double)g[i] / sqrt(var + 1e-5);
        sc[i] = (float)s;
        sh[i] = (float)((double)be[i] - mu * s);
    }
}

// ---------------------------------------------------------------------------
// Gumbel top-K scan: 256 rows/block, one thread per row.
// argmax(softmax((masked+noise)/T)) == argmax over unmasked of (logit + noise)
// noise = -log(-log(u)); strict > keeps first index (jnp.argmax tie-break).
// ---------------------------------------------------------------------------
__global__ __launch_bounds__(256)
void gumbel_topk(const float* __restrict__ logits, const float* __restrict__ u,
                 float* __restrict__ out)
{
    __shared__ __align__(16) float lg[256 * 25];
    __shared__ __align__(16) float us[256 * 25];
    const int tid = threadIdx.x;
    const int r0  = blockIdx.x * 256;

    {
        const float4* src = reinterpret_cast<const float4*>(logits + (size_t)r0 * 25);
        float4* dst = reinterpret_cast<float4*>(lg);
        for (int i = tid; i < 1600; i += 256) dst[i] = src[i];
    }
    __syncthreads();

    float myl[25];
    #pragma unroll
    for (int j = 0; j < 25; ++j) myl[j] = lg[tid * 25 + j];

    unsigned mask = 0x1FFFFFFu;  // 25 ones
    for (int it = 0; it < 15; ++it) {
        __syncthreads();   // protect us[] reuse
        const float4* usrc = reinterpret_cast<const float4*>(u + ((size_t)it * BATCH + r0) * 25);
        float4* ud = reinterpret_cast<float4*>(us);
        for (int i = tid; i < 1600; i += 256) ud[i] = usrc[i];
        __syncthreads();

        float best = -INFINITY;
        int bj = 0;
        #pragma unroll
        for (int j = 0; j < 25; ++j) {
            float uu = us[tid * 25 + j];
            float nz = -logf(-logf(uu));       // accurate logf: argmax must match np fp32
            float v  = myl[j] + nz;
            v = ((mask >> j) & 1u) ? v : -INFINITY;
            if (v > best) { best = v; bj = j; }
        }
        mask &= ~(1u << bj);
        out[(size_t)(r0 + tid) * 15 + it] = (float)bj / 24.0f;
    }
}

extern "C" void kernel_launch(void* const* d_in, const int* in_sizes, int n_in,
                              void* d_out, int out_size, void* d_ws, size_t ws_size,
                              hipStream_t stream)
{
    (void)in_sizes; (void)n_in; (void)out_size; (void)ws_size;
    const float* z   = (const float*)d_in[0];
    const float* u   = (const float*)d_in[1];
    const float* W1  = (const float*)d_in[2];
    const float* b1  = (const float*)d_in[3];
    const float* g1  = (const float*)d_in[4];
    const float* be1 = (const float*)d_in[5];
    const float* W2  = (const float*)d_in[6];
    const float* b2  = (const float*)d_in[7];
    const float* g2  = (const float*)d_in[8];
    const float* be2 = (const float*)d_in[9];
    const float* W3  = (const float*)d_in[10];
    const float* b3  = (const float*)d_in[11];
    const float* g3  = (const float*)d_in[12];
    const float* be3 = (const float*)d_in[13];
    const float* W4  = (const float*)d_in[14];
    const float* b4  = (const float*)d_in[15];
    float* out = (float*)d_out;

    char* ws = (char*)d_ws;
    float* X2     = (float*)ws;                                  // B*256 f32 (later logits)
    float* XA     = (float*)(ws + (size_t)134217728);            // B*128 f32 (X1, then X3)
    char*  statb  = ws + (size_t)134217728 + (size_t)67108864;
    double* sum1 = (double*)statb;      double* sq1 = sum1 + 128;
    double* sum2 = sq1 + 128;           double* sq2 = sum2 + 256;
    double* sum3 = sq2 + 256;           double* sq3 = sum3 + 128;
    float* sc1 = (float*)(sq3 + 128);   float* sh1 = sc1 + 128;
    float* sc2 = sh1 + 128;             float* sh2 = sc2 + 256;
    float* sc3 = sh2 + 256;             float* sh3 = sc3 + 128;
    float* logits = X2;                 // X2 region dead after P3

    hipMemsetAsync(statb, 0, 1024 * sizeof(double), stream);

    // P1: z[B,50] @ W1[50,128] -> X1 (XA) + stats1.  KS=64 single-chunk, LDS 64KB
    gemm_bn<128,128,128, 8,8, 256, 64, 64, 50, false, true>
        <<<BATCH/128, 256, 0, stream>>>(z, W1, b1, nullptr, nullptr, XA, sum1, sq1);
    finalize_bn<<<1, 256, 0, stream>>>(sum1, sq1, g1, be1, sc1, sh1, 128);

    // P2: lrelu(bn(X1)) @ W2[128,256] -> X2 + stats2.  LDS ~41KB
    gemm_bn<64,256,256, 8,8, 256, 16, 128, 128, true, true>
        <<<BATCH/64, 256, 0, stream>>>(XA, W2, b2, sc1, sh1, X2, sum2, sq2);
    finalize_bn<<<1, 256, 0, stream>>>(sum2, sq2, g2, be2, sc2, sh2, 256);

    // P3: lrelu(bn(X2)) @ W3[256,128] -> X3 (XA) + stats3.  LDS ~34KB
    gemm_bn<128,128,128, 8,8, 256, 16, 256, 256, true, true>
        <<<BATCH/128, 256, 0, stream>>>(X2, W3, b3, sc2, sh2, XA, sum3, sq3);
    finalize_bn<<<1, 256, 0, stream>>>(sum3, sq3, g3, be3, sc3, sh3, 128);

    // P3b: lrelu(bn(X3)) @ W4[128,25] -> logits.  LDS ~21KB
    gemm_bn<128,32,25, 4,4, 256, 16, 128, 128, true, false>
        <<<BATCH/128, 256, 0, stream>>>(XA, W4, b4, sc3, sh3, logits, nullptr, nullptr);

    // P4: gumbel top-15 scan
    gumbel_topk<<<BATCH/256, 256, 0, stream>>>(logits, u, out);
}

// Round 5
// 738.588 us; speedup vs baseline: 1.8371x; 1.8371x over previous
//
#include <hip/hip_runtime.h>
#include <math.h>

#define BATCH 131072

// ---------------------------------------------------------------------------
// Fused GEMM + optional input BN-affine/lrelu + optional BN stats accumulate.
// C[r,n] = sum_k f(A[r,k]) * W[k,n] + bias[n],   f = lrelu(x*sc+sh) or identity
//
// - BN finalize FUSED into consumer prologue: every block recomputes sc/sh
//   from the previous layer's double sums (kernel boundary = grid sync).
// - A-tile: row-major [MT][KS], float4-group XOR swizzle (group c4 of row r
//   stored at c4 ^ ((r/TM)&3)) -> compute reads ds_read_b128 conflict-free.
// - B-tile: [KS][NT] linear; thread cols = h*(NCG*4) + tx*4 + 0..3.
// - Single-buffered LDS, direct staging (NO regs live across compute —
//   R3's reg-pipeline evicted acc to scratch: 1.1GB spill traffic).
// ---------------------------------------------------------------------------
template<int MT, int NT, int NSTORE, int TM, int TN, int BLK, int KS, int K,
         bool AFFINE, bool STATS>
__global__ __launch_bounds__(BLK)
void gemm_bn2(const float* __restrict__ Ain, const float* __restrict__ W,
              const float* __restrict__ bias,
              const float* __restrict__ gamma, const float* __restrict__ beta,
              const double* __restrict__ prevSum, const double* __restrict__ prevSq,
              float* __restrict__ Xout_g,
              double* __restrict__ outSum, double* __restrict__ outSq)
{
    constexpr int KC   = (K + KS - 1) / KS;
    constexpr bool TAIL = (K % KS) != 0;
    constexpr int CPR  = KS / 4;              // float4 groups per A row
    constexpr int NCG  = NT / TN;             // col groups
    constexpr int RG   = MT / TM;             // row groups
    constexpr int NH   = TN / 4;              // float4 groups per thread (cols)
    constexpr int AL4  = MT * KS / 4 / BLK;   // A float4 stores per thread
    constexpr bool BVEC = (NT == NSTORE);
    constexpr int BL4  = BVEC ? (KS * NT / 4 / BLK) : 1;
    constexpr int BLS  = BVEC ? 1 : (KS * NT / BLK);
    constexpr int HF   = (TM >= 8) ? 8 : TM;  // a-frag half size
    static_assert(NCG * RG == BLK, "thread mapping");
    static_assert(TM % HF == 0, "half split");
    static_assert(!STATS || 2 * RG * NT <= KS * NT, "stats scratch fits Bs");

    __shared__ float As[MT][KS];
    __shared__ float Bs[KS][NT];
    __shared__ float scs[AFFINE ? K : 1];
    __shared__ float shs[AFFINE ? K : 1];

    const int tid = threadIdx.x;
    const int r0  = blockIdx.x * MT;
    const int tx  = tid % NCG;
    const int ty  = tid / NCG;
    const int key = ty & 3;

    // ---- prologue: fused BN finalize (redundant per block, trivial cost)
    if constexpr (AFFINE) {
        for (int i = tid; i < K; i += BLK) {
            const double inv = 1.0 / (double)BATCH;
            double mu  = prevSum[i] * inv;
            double var = prevSq[i] * inv - mu * mu;
            double s   = (double)gamma[i] / sqrt(var + 1e-5);
            scs[i] = (float)s;
            shs[i] = (float)((double)beta[i] - mu * s);
        }
    }

    float acc[TM][TN] = {};

    for (int kc = 0; kc < KC; ++kc) {
        const int kb = kc * KS;
        __syncthreads();   // chunk 0: scs visible; later: compute(kc-1) done
        // ---- stage A: global -> (affine/lrelu) -> LDS (XOR-swizzled b128)
        #pragma unroll
        for (int l = 0; l < AL4; ++l) {
            int idx = tid + l * BLK;
            int row = idx / CPR;
            int c4  = idx % CPR;
            int gk  = kb + c4 * 4;
            const float* gp = Ain + (size_t)(r0 + row) * K + gk;
            float4 v;
            if constexpr (!TAIL) {
                v = *reinterpret_cast<const float4*>(gp);
            } else {
                if (gk + 4 <= K) v = *reinterpret_cast<const float4*>(gp);
                else {
                    float tt[4];
                    #pragma unroll
                    for (int c = 0; c < 4; ++c) tt[c] = (gk + c < K) ? gp[c] : 0.f;
                    v = make_float4(tt[0], tt[1], tt[2], tt[3]);
                }
            }
            if constexpr (AFFINE) {
                float* vp = &v.x;
                #pragma unroll
                for (int c = 0; c < 4; ++c) {
                    float x = vp[c] * scs[gk + c] + shs[gk + c];
                    vp[c] = x > 0.f ? x : 0.2f * x;
                }
            }
            *reinterpret_cast<float4*>(&As[row][(c4 ^ ((row / TM) & 3)) * 4]) = v;
        }
        // ---- stage B
        if constexpr (BVEC) {
            #pragma unroll
            for (int l = 0; l < BL4; ++l) {
                int idx = tid + l * BLK;
                int kk  = idx / (NT / 4);
                int n4  = idx % (NT / 4);
                int gk  = kb + kk;
                float4 v;
                if constexpr (!TAIL)
                    v = *reinterpret_cast<const float4*>(W + (size_t)gk * NSTORE + n4 * 4);
                else
                    v = (gk < K)
                      ? *reinterpret_cast<const float4*>(W + (size_t)gk * NSTORE + n4 * 4)
                      : make_float4(0.f, 0.f, 0.f, 0.f);
                *reinterpret_cast<float4*>(&Bs[kk][n4 * 4]) = v;
            }
        } else {
            #pragma unroll
            for (int l = 0; l < BLS; ++l) {
                int idx = tid + l * BLK;
                int kk  = idx / NT;
                int n   = idx % NT;
                int gk  = kb + kk;
                Bs[kk][n] = (gk < K && n < NSTORE) ? W[(size_t)gk * NSTORE + n] : 0.f;
            }
        }
        __syncthreads();
        // ---- compute: per k4, B regs once, A in halves of HF rows
        #pragma unroll
        for (int k4 = 0; k4 < CPR; ++k4) {
            const int pf = (k4 ^ key) * 4;
            float4 bq[4][NH];
            #pragma unroll
            for (int kk = 0; kk < 4; ++kk)
                #pragma unroll
                for (int h = 0; h < NH; ++h)
                    bq[kk][h] = *reinterpret_cast<const float4*>(
                        &Bs[k4 * 4 + kk][h * (NCG * 4) + tx * 4]);
            #pragma unroll
            for (int hf = 0; hf < TM / HF; ++hf) {
                float4 a4[HF];
                #pragma unroll
                for (int i = 0; i < HF; ++i)
                    a4[i] = *reinterpret_cast<const float4*>(
                        &As[ty * TM + hf * HF + i][pf]);
                #pragma unroll
                for (int kk = 0; kk < 4; ++kk)
                    #pragma unroll
                    for (int i = 0; i < HF; ++i) {
                        const float av = (&a4[i].x)[kk];
                        const float* bp = &bq[kk][0].x;
                        #pragma unroll
                        for (int j = 0; j < TN; ++j)
                            acc[hf * HF + i][j] = fmaf(av, bp[j], acc[hf * HF + i][j]);
                    }
            }
        }
    }

    // ---- epilogue: bias, store, BN stats
    float bc[TN];
    #pragma unroll
    for (int j = 0; j < TN; ++j) {
        int gc = (j >> 2) * (NCG * 4) + tx * 4 + (j & 3);
        bc[j] = (gc < NSTORE) ? bias[gc] : 0.f;
    }
    float psum[TN] = {}, psq[TN] = {};
    #pragma unroll
    for (int i = 0; i < TM; ++i) {
        int row = r0 + ty * TM + i;
        float x[TN];
        #pragma unroll
        for (int j = 0; j < TN; ++j) {
            x[j] = acc[i][j] + bc[j];
            if (STATS) { psum[j] += x[j]; psq[j] += x[j] * x[j]; }
        }
        if constexpr (BVEC) {
            #pragma unroll
            for (int h = 0; h < NH; ++h) {
                float4 v = make_float4(x[h*4], x[h*4+1], x[h*4+2], x[h*4+3]);
                *reinterpret_cast<float4*>(
                    &Xout_g[(size_t)row * NSTORE + h * (NCG * 4) + tx * 4]) = v;
            }
        } else {
            #pragma unroll
            for (int j = 0; j < TN; ++j) {
                int gc = (j >> 2) * (NCG * 4) + tx * 4 + (j & 3);
                if (gc < NSTORE) Xout_g[(size_t)row * NSTORE + gc] = x[j];
            }
        }
    }
    if constexpr (STATS) {
        __syncthreads();                       // Bs reuse as reduce scratch
        float* S1 = &Bs[0][0];
        float* S2 = S1 + RG * NT;
        #pragma unroll
        for (int j = 0; j < TN; ++j) {
            int gc = (j >> 2) * (NCG * 4) + tx * 4 + (j & 3);
            S1[ty * NT + gc] = psum[j];
            S2[ty * NT + gc] = psq[j];
        }
        __syncthreads();
        if (tid < NT) {
            double s = 0.0, q = 0.0;
            #pragma unroll 4
            for (int t = 0; t < RG; ++t) {
                s += (double)S1[t * NT + tid];
                q += (double)S2[t * NT + tid];
            }
            atomicAdd(&outSum[tid], s);
            atomicAdd(&outSq[tid], q);
        }
    }
}

// ---------------------------------------------------------------------------
// Gumbel top-K scan: 256 rows/block, one thread per row, double-buffered u
// tile with register prefetch (one barrier per iteration).
// argmax(softmax((masked+noise)/T)) == argmax over unmasked of (logit+noise),
// noise = -log(-log(u)); strict > keeps first index (jnp.argmax tie-break).
// ---------------------------------------------------------------------------
__global__ __launch_bounds__(256)
void gumbel_topk(const float* __restrict__ logits, const float* __restrict__ u,
                 float* __restrict__ out)
{
    __shared__ __align__(16) float lg[256 * 25];
    __shared__ __align__(16) float us[2][256 * 25];
    const int tid = threadIdx.x;
    const int r0  = blockIdx.x * 256;

    {
        const float4* src = reinterpret_cast<const float4*>(logits + (size_t)r0 * 25);
        float4* dst = reinterpret_cast<float4*>(lg);
        #pragma unroll
        for (int l = 0; l < 7; ++l) {
            int i = tid + l * 256;
            if (i < 1600) dst[i] = src[i];
        }
        const float4* u0 = reinterpret_cast<const float4*>(u + (size_t)r0 * 25);
        float4* d0 = reinterpret_cast<float4*>(us[0]);
        #pragma unroll
        for (int l = 0; l < 7; ++l) {
            int i = tid + l * 256;
            if (i < 1600) d0[i] = u0[i];
        }
    }
    __syncthreads();

    float myl[25];
    #pragma unroll
    for (int j = 0; j < 25; ++j) myl[j] = lg[tid * 25 + j];

    unsigned mask = 0x1FFFFFFu;  // 25 ones
    for (int it = 0; it < 15; ++it) {
        const int cur = it & 1;
        // prefetch next iteration's u tile into registers (latency hides
        // under the logf chain below)
        float4 t[7];
        const bool have = (it + 1) < 15;
        if (have) {
            const float4* un = reinterpret_cast<const float4*>(
                u + ((size_t)(it + 1) * BATCH + r0) * 25);
            #pragma unroll
            for (int l = 0; l < 7; ++l) {
                int i = tid + l * 256;
                if (i < 1600) t[l] = un[i];
            }
        }

        float best = -INFINITY;
        int bj = 0;
        #pragma unroll
        for (int j = 0; j < 25; ++j) {
            float uu = us[cur][tid * 25 + j];
            float nz = -logf(-logf(uu));   // accurate logf: argmax must match np fp32
            float v  = myl[j] + nz;
            v = ((mask >> j) & 1u) ? v : -INFINITY;
            if (v > best) { best = v; bj = j; }
        }
        mask &= ~(1u << bj);
        out[(size_t)(r0 + tid) * 15 + it] = (float)bj / 24.0f;

        if (have) {
            float4* dn = reinterpret_cast<float4*>(us[cur ^ 1]);
            #pragma unroll
            for (int l = 0; l < 7; ++l) {
                int i = tid + l * 256;
                if (i < 1600) dn[i] = t[l];
            }
        }
        __syncthreads();
    }
}

extern "C" void kernel_launch(void* const* d_in, const int* in_sizes, int n_in,
                              void* d_out, int out_size, void* d_ws, size_t ws_size,
                              hipStream_t stream)
{
    (void)in_sizes; (void)n_in; (void)out_size; (void)ws_size;
    const float* z   = (const float*)d_in[0];
    const float* u   = (const float*)d_in[1];
    const float* W1  = (const float*)d_in[2];
    const float* b1  = (const float*)d_in[3];
    const float* g1  = (const float*)d_in[4];
    const float* be1 = (const float*)d_in[5];
    const float* W2  = (const float*)d_in[6];
    const float* b2  = (const float*)d_in[7];
    const float* g2  = (const float*)d_in[8];
    const float* be2 = (const float*)d_in[9];
    const float* W3  = (const float*)d_in[10];
    const float* b3  = (const float*)d_in[11];
    const float* g3  = (const float*)d_in[12];
    const float* be3 = (const float*)d_in[13];
    const float* W4  = (const float*)d_in[14];
    const float* b4  = (const float*)d_in[15];
    float* out = (float*)d_out;

    char* ws = (char*)d_ws;
    float* X2     = (float*)ws;                                  // B*256 f32 (later logits)
    float* XA     = (float*)(ws + (size_t)134217728);            // B*128 f32 (X1, then X3)
    char*  statb  = ws + (size_t)134217728 + (size_t)67108864;
    double* sum1 = (double*)statb;      double* sq1 = sum1 + 128;
    double* sum2 = sq1 + 128;           double* sq2 = sum2 + 256;
    double* sum3 = sq2 + 256;           double* sq3 = sum3 + 128;
    float* logits = X2;                 // X2 region dead after P3

    (void)hipMemsetAsync(statb, 0, 1024 * sizeof(double), stream);

    // P1: z[B,50] @ W1[50,128] -> X1 (XA) + stats1.   MT=256,TM=16, KS=32 (tail)
    gemm_bn2<256,128,128, 16,8, 256, 32, 50, false, true>
        <<<BATCH/256, 256, 0, stream>>>(z, W1, b1, nullptr, nullptr,
                                        nullptr, nullptr, XA, sum1, sq1);

    // P2: lrelu(bn(X1)) @ W2[128,256] -> X2 + stats2.  MT=128,TM=16
    gemm_bn2<128,256,256, 16,8, 256, 32, 128, true, true>
        <<<BATCH/128, 256, 0, stream>>>(XA, W2, b2, g1, be1,
                                        sum1, sq1, X2, sum2, sq2);

    // P3: lrelu(bn(X2)) @ W3[256,128] -> X3 (XA) + stats3.  MT=256,TM=16
    gemm_bn2<256,128,128, 16,8, 256, 32, 256, true, true>
        <<<BATCH/256, 256, 0, stream>>>(X2, W3, b3, g2, be2,
                                        sum2, sq2, XA, sum3, sq3);

    // P3b: lrelu(bn(X3)) @ W4[128,25] -> logits.  MT=256,TM=4,TN=8
    gemm_bn2<256,32,25, 4,8, 256, 32, 128, true, false>
        <<<BATCH/256, 256, 0, stream>>>(XA, W4, b4, g3, be3,
                                        sum3, sq3, logits, nullptr, nullptr);

    // P4: gumbel top-15 scan
    gumbel_topk<<<BATCH/256, 256, 0, stream>>>(logits, u, out);
}